// Round 10
// baseline (302.229 us; speedup 1.0000x reference)
//
#include <hip/hip_runtime.h>
#include <hip/hip_bf16.h>

#define T_TOK 2048
#define HDIM 1024
#define IDIM 512
#define ISDIM 1024
#define NEXP 16
#define TOPK 4
#define NSLOT (T_TOK*TOPK)
#define SCALE_F 2.5f

typedef unsigned short u16;
typedef float f32x4 __attribute__((ext_vector_type(4)));
typedef __bf16 bf16x8 __attribute__((ext_vector_type(8)));
typedef u16 u16x8 __attribute__((ext_vector_type(8)));

__device__ __forceinline__ u16 f2bf(float f) {
  unsigned u = __builtin_bit_cast(unsigned, f);
  u += 0x7fffu + ((u >> 16) & 1u);   // round-to-nearest-even
  return (u16)(u >> 16);
}

__device__ __forceinline__ float bf2f(u16 h) {
  unsigned u = ((unsigned)h) << 16;
  return __builtin_bit_cast(float, u);
}

__device__ __forceinline__ void gload_lds16(const u16* g, u16* l) {
  // async global->LDS, 16B/lane; data lands at (wave-uniform l) + lane*16
  __builtin_amdgcn_global_load_lds(
      (const __attribute__((address_space(1))) void*)g,
      (__attribute__((address_space(3))) void*)l, 16, 0, 0);
}

__device__ __forceinline__ f32x4 mfma16(u16x8 a, u16x8 b, f32x4 c) {
  return __builtin_amdgcn_mfma_f32_16x16x32_bf16(
      __builtin_bit_cast(bf16x8, a), __builtin_bit_cast(bf16x8, b), c, 0, 0, 0);
}

// counted waits (T4): NEVER vmcnt(0) in the main loop — loads stay in
// flight across barriers. rule 18: sched_barrier(0) after lgkmcnt(0).
__device__ __forceinline__ void wait_vm6()   { asm volatile("s_waitcnt vmcnt(6)" ::: "memory"); }
__device__ __forceinline__ void wait_vm0()   { asm volatile("s_waitcnt vmcnt(0)" ::: "memory"); }
__device__ __forceinline__ void wait_lgkm0() { asm volatile("s_waitcnt lgkmcnt(0)" ::: "memory"); }

// compact tile-list sizing (worst case): sum_e ceil(cnt_e/64) <= 144
// phase0 tiles <= 144*4 + 256 = 832  -> JMAX0 = 832/8 + 32 = 136
// phase1 tiles <= 144*8 + 256 = 1408 -> JMAX1 = 1408/8 + 32 = 208
#define JMAX0 136
#define G0T (8*JMAX0)
#define JMAX1 208
#define G1T (8*JMAX1)
#define MAXG0 96
#define MAXG1 192

// weight-conversion block counts (1 float4/thread, 256 threads/block)
#define N1Q (NEXP*IDIM*HDIM/4)
#define N2Q (NEXP*HDIM*IDIM/4)
#define NSQ (ISDIM*HDIM/4)
#define CVTB ((N1Q + NSQ) / 256)        // 9216 blocks (same for phase-1 set)

__device__ __forceinline__ void cvt_f4(const float* src, u16* dst, int off) {
  float4 v = reinterpret_cast<const float4*>(src)[off];
  ushort4 o;
  o.x = f2bf(v.x); o.y = f2bf(v.y); o.z = f2bf(v.z); o.w = f2bf(v.w);
  reinterpret_cast<ushort4*>(dst)[off] = o;
}

// ---------------- router + W1/Ws1 conversion (overlapped) -----------------
// v13: hist_kernel folded in — tid0 does 4 global atomicAdds on counts[]
// (8192 atomics spread over router's execution, hidden). counts/gfill are
// zeroed by hipMemsetAsync before launch (no in-kernel zero race).
// Blocks >= T_TOK convert W1/Ws1 while router blocks run.
__global__ void __launch_bounds__(256) router_kernel(
    const float* __restrict__ x, const float* __restrict__ Wg,
    const float* __restrict__ bias,
    int* __restrict__ topk_idx, float* __restrict__ topk_w,
    u16* __restrict__ Xbf, int* __restrict__ counts,
    const float* __restrict__ W1, const float* __restrict__ Ws1,
    u16* __restrict__ W1b, u16* __restrict__ Ws1b) {
  int t = blockIdx.x;
  int tid = threadIdx.x;

  if (t >= T_TOK) {            // weight-conversion blocks (block-uniform)
    int i = (t - T_TOK) * 256 + tid;
    if (i < N1Q) cvt_f4(W1, W1b, i);
    else         cvt_f4(Ws1, Ws1b, i - N1Q);
    return;
  }

  int lane = tid & 63;
  int wave = tid >> 6;

  __shared__ __align__(16) float sx[HDIM];
  __shared__ float ssc[NEXP];

  float4 xv = reinterpret_cast<const float4*>(x + (size_t)t * HDIM)[tid];
  reinterpret_cast<float4*>(sx)[tid] = xv;
  ushort4 o;
  o.x = f2bf(xv.x); o.y = f2bf(xv.y); o.z = f2bf(xv.z); o.w = f2bf(xv.w);
  reinterpret_cast<ushort4*>(Xbf + (size_t)t * HDIM)[tid] = o;
  __syncthreads();

  float acc[4] = {0.f, 0.f, 0.f, 0.f};
  const float4* sx4 = reinterpret_cast<const float4*>(sx);
#pragma unroll
  for (int c = 0; c < 4; c++) {
    float4 xq = sx4[lane + 64 * c];
#pragma unroll
    for (int e = 0; e < 4; e++) {
      float4 wq = reinterpret_cast<const float4*>(
          Wg + (size_t)(wave * 4 + e) * HDIM)[lane + 64 * c];
      acc[e] += xq.x * wq.x + xq.y * wq.y + xq.z * wq.z + xq.w * wq.w;
    }
  }
#pragma unroll
  for (int e = 0; e < 4; e++) {
    float v = acc[e];
#pragma unroll
    for (int off = 32; off > 0; off >>= 1) v += __shfl_xor(v, off);
    if (lane == 0) ssc[wave * 4 + e] = v;
  }
  __syncthreads();

  if (tid == 0) {
    float scores[NEXP], sc[NEXP];
#pragma unroll
    for (int e = 0; e < NEXP; e++) {
      float s = 1.f / (1.f + expf(-ssc[e]));
      scores[e] = s;
      sc[e] = s + bias[e];
    }
    float gsum[4];
#pragma unroll
    for (int g = 0; g < 4; g++) {
      float a = sc[4*g], b = sc[4*g+1], c = sc[4*g+2], d = sc[4*g+3];
      float hi1 = fmaxf(a, b), lo1 = fminf(a, b);
      float hi2 = fmaxf(c, d), lo2 = fminf(c, d);
      gsum[g] = fmaxf(hi1, hi2) + fmaxf(fminf(hi1, hi2), fmaxf(lo1, lo2));
    }
    int g0 = 0; float bv = gsum[0];
#pragma unroll
    for (int g = 1; g < 4; g++) if (gsum[g] > bv) { bv = gsum[g]; g0 = g; }
    int g1 = -1; float bv2 = -1e30f;
#pragma unroll
    for (int g = 0; g < 4; g++) if (g != g0 && gsum[g] > bv2) { bv2 = gsum[g]; g1 = g; }
    float m[NEXP];
#pragma unroll
    for (int e = 0; e < NEXP; e++) {
      int g = e >> 2;
      m[e] = (g == g0 || g == g1) ? sc[e] : 0.0f;
    }
    int idx[TOPK]; float w[TOPK];
#pragma unroll
    for (int k = 0; k < TOPK; k++) {
      int bj = 0; float bmv = m[0];
#pragma unroll
      for (int j = 1; j < NEXP; j++) if (m[j] > bmv) { bmv = m[j]; bj = j; }
      idx[k] = bj; w[k] = scores[bj];
#pragma unroll
      for (int j = 0; j < NEXP; j++) m[j] = (j == bj) ? -1e30f : m[j];
    }
    float s4 = w[0] + w[1] + w[2] + w[3] + 1e-20f;
    float inv = SCALE_F / s4;
#pragma unroll
    for (int k = 0; k < TOPK; k++) {
      topk_idx[t * TOPK + k] = idx[k];
      topk_w[t * TOPK + k] = w[k] * inv;
      atomicAdd(&counts[idx[k]], 1);          // folded histogram
    }
  }
}

// ---------------- scatter_build: 33 blocks ---------------------------------
// blocks 0-31: scatter 1 slot/thread (wave-aggregated atomics on gfill);
// block 32: greedy tile-list builders (concurrent with scatter).
__global__ void __launch_bounds__(256) scatter_build(
    const int* __restrict__ topk_idx, const float* __restrict__ topk_w,
    const int* __restrict__ counts, int* __restrict__ offsets,
    int* __restrict__ gfill,
    int* __restrict__ perm_token, float* __restrict__ perm_w,
    int* __restrict__ slot_of,
    int* __restrict__ tiles0, int* __restrict__ tiles1) {
  int b = blockIdx.x;
  int tid = threadIdx.x;
  int lane = tid & 63;

  if (b < 32) {
    int c = (lane < NEXP) ? counts[lane] : 0;
    int incl = c;
#pragma unroll
    for (int o = 1; o < 16; o <<= 1) {
      int v = __shfl_up(incl, o);
      if (lane >= o) incl += v;
    }
    int excl = incl - c;

    int j = b * 256 + tid;
    int e = topk_idx[j];
    unsigned long long m = ~0ull;
#pragma unroll
    for (int bb = 0; bb < 4; bb++) {
      unsigned long long bl = __ballot((e >> bb) & 1);
      m &= ((e >> bb) & 1) ? bl : ~bl;
    }
    int leader = __ffsll(m) - 1;
    int rank = __popcll(m & ((1ull << lane) - 1ull));
    int base = 0;
    if (lane == leader) base = atomicAdd(&gfill[e], __popcll(m));
    base = __shfl(base, leader);
    int pos = __shfl(excl, e) + base + rank;
    perm_token[pos] = j >> 2;
    perm_w[pos] = topk_w[j];
    slot_of[j] = pos;
    if (b == 0 && tid < NEXP) offsets[tid] = excl;
    return;
  }

  __shared__ int hcnt[NEXP];
  __shared__ int g0s[MAXG0], g0c[MAXG0], g0n[MAXG0];
  __shared__ int g1s[MAXG1], g1c[MAXG1], g1n[MAXG1];
  __shared__ int sng0, sng1;
  if (tid < NEXP) hcnt[tid] = counts[tid];
  __syncthreads();

  if (tid == 0) {            // phase-0 builder (register greedy)
    int l0=0,l1=0,l2=0,l3=0,l4=0,l5=0,l6=0,l7=0;
    int ng = 0;
#define PLACE0(code0, cn)                                               \
    { int x = 0, lv = l0;                                               \
      if (l1<lv){lv=l1;x=1;} if (l2<lv){lv=l2;x=2;}                     \
      if (l3<lv){lv=l3;x=3;} if (l4<lv){lv=l4;x=4;}                     \
      if (l5<lv){lv=l5;x=5;} if (l6<lv){lv=l6;x=6;}                     \
      if (l7<lv){lv=l7;x=7;}                                            \
      g0s[ng] = x + 8*lv; g0c[ng] = (code0); g0n[ng] = (cn); ng++;      \
      if (x==0)l0+=(cn); else if (x==1)l1+=(cn); else if (x==2)l2+=(cn);\
      else if (x==3)l3+=(cn); else if (x==4)l4+=(cn);                   \
      else if (x==5)l5+=(cn); else if (x==6)l6+=(cn); else l7+=(cn); }
    for (int nb = 0; nb < 8; nb++) PLACE0((16 << 10) | nb, 32);
    for (int e = 0; e < NEXP; e++) {
      int mc = (hcnt[e] + 63) >> 6;
      for (int nb = 0; nb < 4; nb++)
        for (int base = 0; base < mc; base += 32)
          PLACE0((e << 10) | (base << 3) | nb, min(32, mc - base));
    }
    sng0 = ng;
#undef PLACE0
  }
  if (tid == 64) {           // phase-1 builder: shared now UNSPLIT (1x K)
    int l0=0,l1=0,l2=0,l3=0,l4=0,l5=0,l6=0,l7=0;
    int ng = 0;
#define PLACE1(code0, cn)                                               \
    { int x = 0, lv = l0;                                               \
      if (l1<lv){lv=l1;x=1;} if (l2<lv){lv=l2;x=2;}                     \
      if (l3<lv){lv=l3;x=3;} if (l4<lv){lv=l4;x=4;}                     \
      if (l5<lv){lv=l5;x=5;} if (l6<lv){lv=l6;x=6;}                     \
      if (l7<lv){lv=l7;x=7;}                                            \
      g1s[ng] = x + 8*lv; g1c[ng] = (code0); g1n[ng] = (cn); ng++;      \
      if (x==0)l0+=(cn); else if (x==1)l1+=(cn); else if (x==2)l2+=(cn);\
      else if (x==3)l3+=(cn); else if (x==4)l4+=(cn);                   \
      else if (x==5)l5+=(cn); else if (x==6)l6+=(cn); else l7+=(cn); }
    for (int nb = 0; nb < 8; nb++) PLACE1((16 << 10) | nb, 32);
    for (int e = 0; e < NEXP; e++) {
      int mc = (hcnt[e] + 63) >> 6;
      for (int nb = 0; nb < 8; nb++)
        for (int base = 0; base < mc; base += 32)
          PLACE1((e << 10) | (base << 3) | nb, min(32, mc - base));
    }
    sng1 = ng;
#undef PLACE1
  }
  if (tid >= 128) {
    for (int i = tid - 128; i < G0T; i += 128) tiles0[i] = -1;
    for (int i = tid - 128; i < G1T; i += 128) tiles1[i] = -1;
  }
  __syncthreads();

  int ng0 = sng0, ng1 = sng1;
  for (int g = tid; g < ng0; g += 256) {
    int st = g0s[g], c0 = g0c[g], cn = g0n[g];
    for (int mm = 0; mm < cn; mm++) tiles0[st + 8 * mm] = c0 + (mm << 3);
  }
  for (int g = tid; g < ng1; g += 256) {
    int st = g1s[g], c0 = g1c[g], cn = g1n[g];
    for (int mm = 0; mm < cn; mm++) tiles1[st + 8 * mm] = c0 + (mm << 3);
  }
}

// ---------------- fused MoE GEMM: 64x128, BK=64, counted-vmcnt pipeline ----
// v13: phase-1 shared expert UNSPLIT over K (runtime NT=16 vs routed 8):
// split-K fp32 Ys (16MB w + 16MB r) -> single bf16 Ysb (4MB w + 4MB r).
// Accumulation stays fp32 in AGPRs; one bf16 round, same as routed path.
// PHASE 0 carries 9216 blocks converting W2/Ws2 for phase 1 (overlap).
#define BM 64
#define BN 128
#define BK 64

template<int PHASE>
__global__ void __launch_bounds__(256) moe_gemm(
    const int* __restrict__ tiles,
    const u16* __restrict__ Xbf, const u16* __restrict__ Hg,
    const u16* __restrict__ Hs,
    const u16* __restrict__ W1b, const u16* __restrict__ W2b,
    const u16* __restrict__ Ws1b, const u16* __restrict__ Ws2b,
    const float* __restrict__ W2f, const float* __restrict__ Ws2f,
    u16* __restrict__ W2bo, u16* __restrict__ Ws2bo,
    const int* __restrict__ eoffs, const int* __restrict__ ecnts,
    const int* __restrict__ rowmap, const float* __restrict__ rowscale,
    u16* __restrict__ HgOut, u16* __restrict__ HsOut,
    u16* __restrict__ Ygb, u16* __restrict__ Ysb)
{
  if (PHASE == 0 && blockIdx.x >= G0T) {   // overlapped W2/Ws2 conversion
    int i = (blockIdx.x - G0T) * 256 + threadIdx.x;
    if (i < N2Q) cvt_f4(W2f, W2bo, i);
    else         cvt_f4(Ws2f, Ws2bo, i - N2Q);
    return;
  }

  int code = tiles[blockIdx.x];
  if (code < 0) return;                            // block-uniform exit
  int e  = code >> 10;
  int mb = (code >> 3) & 127;
  int nb = code & 7;

  bool sh = (e >= NEXP);
  int N, Mloc, rowbase, Astr, Bstr;
  int NT;                                          // runtime K-tile count
  const u16* Abase;
  const u16* Bp;
  if (PHASE == 0) {
    Astr = HDIM; Bstr = HDIM; NT = HDIM / BK;
    if (sh) { N = ISDIM; Mloc = T_TOK; rowbase = 0; Abase = Xbf; Bp = Ws1b; }
    else    { N = IDIM; Mloc = ecnts[e]; rowbase = eoffs[e]; Abase = Xbf;
              Bp = W1b + (size_t)e * IDIM * HDIM; }
  } else {
    N = HDIM;
    if (sh) { Astr = ISDIM; Bstr = ISDIM; NT = ISDIM / BK;   // unsplit K
              Mloc = T_TOK; rowbase = 0; Abase = Hs; Bp = Ws2b; }
    else    { Astr = IDIM; Bstr = IDIM; NT = IDIM / BK;
              Mloc = ecnts[e]; rowbase = eoffs[e]; Abase = Hg;
              Bp = W2b + (size_t)e * HDIM * IDIM; }
  }
  int m0 = mb * BM;
  if (m0 >= Mloc) return;
  int n0 = nb * BN;
  if (n0 >= N) return;

  // unpadded: required by global_load_lds lane->base+lane*16 placement
  __shared__ __align__(16) u16 sA[2][BM * BK];   // 2 x 8 KB
  __shared__ __align__(16) u16 sB[2][BN * BK];   // 2 x 16 KB

  int tid = threadIdx.x;
  int lane = tid & 63;
  int wave = tid >> 6;
  int wm = (wave >> 1) * 32;   // wave computes 32x64 of the 64x128 tile
  int wn = (wave & 1) * 64;
  int fm = lane & 15;
  int kq = lane >> 4;          // 0..3
  int fsw = fm & 7;            // row&7 for fragment-row fm

  // staging: lane -> row (lane>>3), LDS chunk (lane&7); source chunk is
  // XOR-swizzled so LDS chunk l of row r holds global chunk l ^ (r&7)
  int lrow8 = lane >> 3;       // 0..7
  int sch = ((lane & 7) ^ lrow8) * 8;   // swizzled source k-offset (elems)

  // A: wave stages tile rows [16w,16w+16) via 2 gloads of 8 rows
  const u16* AgP[2];
  int aoff[2];
#pragma unroll
  for (int g = 0; g < 2; g++) {
    int rt = 16 * wave + 8 * g + lrow8;
    int ar = m0 + rt;
    int arc = (ar < Mloc) ? ar : (Mloc - 1);        // clamp; stores masked
    size_t asrc;
    if (PHASE == 0 && !sh) asrc = (size_t)rowmap[rowbase + arc] * Astr;
    else                   asrc = (size_t)((sh ? 0 : rowbase) + arc) * Astr;
    AgP[g] = Abase + asrc + sch;
    aoff[g] = (16 * wave + 8 * g) * BK;
  }
  // B: wave stages tile rows [32w,32w+32) via 4 gloads of 8 rows
  const u16* BgP[4];
  int boff[4];
#pragma unroll
  for (int g = 0; g < 4; g++) {
    int rt = 32 * wave + 8 * g + lrow8;
    BgP[g] = Bp + (size_t)(n0 + rt) * Bstr + sch;
    boff[g] = (32 * wave + 8 * g) * BK;
  }

  f32x4 acc[2][4] = {};

  // prologue: stage tiles 0 and 1 (6 gloads each, per wave)
#pragma unroll
  for (int g = 0; g < 2; g++) gload_lds16(AgP[g], &sA[0][aoff[g]]);
#pragma unroll
  for (int g = 0; g < 4; g++) gload_lds16(BgP[g], &sB[0][boff[g]]);
#pragma unroll
  for (int g = 0; g < 2; g++) gload_lds16(AgP[g] + BK, &sA[1][aoff[g]]);
#pragma unroll
  for (int g = 0; g < 4; g++) gload_lds16(BgP[g] + BK, &sB[1][boff[g]]);

  // main loop: tiles 0..NT-2 with counted vmcnt(6); tail tile drains
  for (int t = 0; t < NT - 1; ++t) {
    int cur = t & 1;
    wait_vm6();                        // tile t's 6 done; t+1's 6 in flight
    __builtin_amdgcn_s_barrier();      // all waves: buf[cur] fully staged
    u16x8 af[2][2], bf[2][4];
#pragma unroll
    for (int ks = 0; ks < 2; ks++) {
      int ch = ((ks * 4 + kq) ^ fsw) * 8;   // un-swizzle at read
#pragma unroll
      for (int i = 0; i < 2; i++)
        af[ks][i] = *reinterpret_cast<const u16x8*>(&sA[cur][(wm + 16 * i + fm) * BK + ch]);
#pragma unroll
      for (int j = 0; j < 4; j++)
        bf[ks][j] = *reinterpret_cast<const u16x8*>(&sB[cur][(wn + 16 * j + fm) * BK + ch]);
    }
    wait_lgkm0();
    __builtin_amdgcn_sched_barrier(0);  // rule 18: pin MFMA below the wait
    __builtin_amdgcn_s_barrier();       // all waves done reading buf[cur]
    if (t + 2 < NT) {                   // overwrite buf[cur] with tile t+2
#pragma unroll
      for (int g = 0; g < 2; g++) gload_lds16(AgP[g] + (t + 2) * BK, &sA[cur][aoff[g]]);
#pragma unroll
      for (int g = 0; g < 4; g++) gload_lds16(BgP[g] + (t + 2) * BK, &sB[cur][boff[g]]);
    }
#pragma unroll
    for (int ks = 0; ks < 2; ks++)
#pragma unroll
      for (int i = 0; i < 2; i++)
#pragma unroll
        for (int j = 0; j < 4; j++)
          acc[i][j] = mfma16(af[ks][i], bf[ks][j], acc[i][j]);
  }
  {  // tail: tile NT-1 (only its 6 loads remain in flight)
    int cur = (NT - 1) & 1;
    wait_vm0();
    __builtin_amdgcn_s_barrier();
    u16x8 af[2][2], bf[2][4];
#pragma unroll
    for (int ks = 0; ks < 2; ks++) {
      int ch = ((ks * 4 + kq) ^ fsw) * 8;
#pragma unroll
      for (int i = 0; i < 2; i++)
        af[ks][i] = *reinterpret_cast<const u16x8*>(&sA[cur][(wm + 16 * i + fm) * BK + ch]);
#pragma unroll
      for (int j = 0; j < 4; j++)
        bf[ks][j] = *reinterpret_cast<const u16x8*>(&sB[cur][(wn + 16 * j + fm) * BK + ch]);
    }
    wait_lgkm0();
    __builtin_amdgcn_sched_barrier(0);
#pragma unroll
    for (int ks = 0; ks < 2; ks++)
#pragma unroll
      for (int i = 0; i < 2; i++)
#pragma unroll
        for (int j = 0; j < 4; j++)
          acc[i][j] = mfma16(af[ks][i], bf[ks][j], acc[i][j]);
  }

  // epilogue: C/D mapping col = lane&15, row = (lane>>4)*4 + reg (m89/m91)
#pragma unroll
  for (int i = 0; i < 2; i++) {
#pragma unroll
    for (int r = 0; r < 4; r++) {
      int gm = m0 + wm + 16 * i + kq * 4 + r;
      if (gm < Mloc) {
        float rs = 0.f;
        if (PHASE == 0 && !sh) rs = rowscale[rowbase + gm];
#pragma unroll
        for (int j = 0; j < 4; j++) {
          int gn = n0 + wn + 16 * j + fm;
          float v = acc[i][j][r];
          if (PHASE == 0) {
            float tq = fmaxf(v, 0.f);
            if (!sh) {
              tq = tq * tq * rs;
              HgOut[(size_t)(rowbase + gm) * IDIM + gn] = f2bf(tq);
            } else {
              HsOut[(size_t)gm * ISDIM + gn] = f2bf(tq * tq);
            }
          } else {
            if (!sh) Ygb[(size_t)(rowbase + gm) * HDIM + gn] = f2bf(v);
            else     Ysb[(size_t)gm * HDIM + gn] = f2bf(v);   // unsplit
          }
        }
      }
    }
  }
}

// ---- combine: out[t] = Ysb[t] + sum_k Ygb[slot_of[t,k]] (all bf16) -------
__global__ void __launch_bounds__(256) combine_kernel(
    const u16* __restrict__ Ygb, const u16* __restrict__ Ysb,
    const int* __restrict__ slot_of, float* __restrict__ out) {
  int t = blockIdx.x;
  int i = threadIdx.x;                       // 256 x 4 elems = 1024
  int4 s = *reinterpret_cast<const int4*>(&slot_of[t * 4]);
  const ushort4* Y4 = reinterpret_cast<const ushort4*>(Ygb);
  const ushort4* S4 = reinterpret_cast<const ushort4*>(Ysb);
  float4* O4 = reinterpret_cast<float4*>(out);
  ushort4 sv = S4[(size_t)t * 256 + i];
  ushort4 a = Y4[(size_t)s.x * 256 + i];
  ushort4 b = Y4[(size_t)s.y * 256 + i];
  ushort4 c = Y4[(size_t)s.z * 256 + i];
  ushort4 d = Y4[(size_t)s.w * 256 + i];
  float4 v;
  v.x = bf2f(sv.x) + bf2f(a.x) + bf2f(b.x) + bf2f(c.x) + bf2f(d.x);
  v.y = bf2f(sv.y) + bf2f(a.y) + bf2f(b.y) + bf2f(c.y) + bf2f(d.y);
  v.z = bf2f(sv.z) + bf2f(a.z) + bf2f(b.z) + bf2f(c.z) + bf2f(d.z);
  v.w = bf2f(sv.w) + bf2f(a.w) + bf2f(b.w) + bf2f(c.w) + bf2f(d.w);
  O4[(size_t)t * 256 + i] = v;
}

// ---------------- launcher ----------------
extern "C" void kernel_launch(void* const* d_in, const int* in_sizes, int n_in,
                              void* d_out, int out_size, void* d_ws, size_t ws_size,
                              hipStream_t stream) {
  const float* x    = (const float*)d_in[0];
  const float* Wg   = (const float*)d_in[1];
  const float* bias = (const float*)d_in[2];
  const float* W1   = (const float*)d_in[3];
  const float* W2   = (const float*)d_in[4];
  const float* Ws1  = (const float*)d_in[5];
  const float* Ws2  = (const float*)d_in[6];
  float* out = (float*)d_out;

  char* p = (char*)d_ws;
  auto alloc = [&](size_t bytes) -> void* {
    void* r = (void*)p;
    p += (bytes + 255) & ~(size_t)255;
    return r;
  };
  int*   topk_idx   = (int*)  alloc((size_t)NSLOT * 4);
  float* topk_w     = (float*)alloc((size_t)NSLOT * 4);
  int*   counts     = (int*)  alloc(64);     // ┐ contiguous 256B-aligned
  int*   offsets    = (int*)  alloc(64);     // │ trio zeroed by one memset
  int*   gfill      = (int*)  alloc(64);     // ┘ (offsets rewritten later)
  int*   perm_token = (int*)  alloc((size_t)NSLOT * 4);
  float* perm_w     = (float*)alloc((size_t)NSLOT * 4);
  int*   slot_of    = (int*)  alloc((size_t)NSLOT * 4);
  int*   tiles0     = (int*)  alloc((size_t)G0T * 4);
  int*   tiles1     = (int*)  alloc((size_t)G1T * 4);
  u16*   Xbf        = (u16*)  alloc((size_t)T_TOK * HDIM * 2);
  u16*   W1b        = (u16*)  alloc((size_t)NEXP * IDIM * HDIM * 2);
  u16*   W2b        = (u16*)  alloc((size_t)NEXP * HDIM * IDIM * 2);
  u16*   Ws1b      = (u16*)  alloc((size_t)ISDIM * HDIM * 2);
  u16*   Ws2b      = (u16*)  alloc((size_t)HDIM * ISDIM * 2);
  u16*   Hg         = (u16*)  alloc((size_t)NSLOT * IDIM * 2);
  u16*   Hs         = (u16*)  alloc((size_t)T_TOK * ISDIM * 2);
  u16*   Ygb        = (u16*)  alloc((size_t)NSLOT * HDIM * 2);
  u16*   Ysb        = (u16*)  alloc((size_t)T_TOK * HDIM * 2);

  // zero counts/offsets/gfill (contiguous 3x256B region from counts)
  hipMemsetAsync(counts, 0, 768, stream);

  // router (+ folded histogram) + overlapped W1/Ws1 conversion
  router_kernel<<<T_TOK + CVTB, 256, 0, stream>>>(
      x, Wg, bias, topk_idx, topk_w, Xbf, counts, W1, Ws1, W1b, Ws1b);
  scatter_build<<<33, 256, 0, stream>>>(topk_idx, topk_w, counts, offsets,
                                        gfill, perm_token, perm_w, slot_of,
                                        tiles0, tiles1);

  // phase A: routed up + shared up, plus overlapped W2/Ws2 conversion
  moe_gemm<0><<<G0T + CVTB, 256, 0, stream>>>(
      tiles0, Xbf, Hg, Hs, W1b, W2b, Ws1b, Ws2b, W2, Ws2, W2b, Ws2b,
      offsets, counts, perm_token, perm_w, Hg, Hs, nullptr, nullptr);

  // phase B: routed down (K=512) + shared down UNSPLIT (K=1024)
  moe_gemm<1><<<G1T, 256, 0, stream>>>(
      tiles1, Xbf, Hg, Hs, W1b, W2b, Ws1b, Ws2b, W2, Ws2, W2b, Ws2b,
      offsets, counts, perm_token, perm_w, Hg, Hs, Ygb, Ysb);

  // combine: out[t] = Ysb + sum_k Ygb[slot_of[t,k]]
  combine_kernel<<<T_TOK, 256, 0, stream>>>(Ygb, Ysb, slot_of, out);
}

// Round 11
// 218.471 us; speedup vs baseline: 1.3834x; 1.3834x over previous
//
#include <hip/hip_runtime.h>
#include <hip/hip_bf16.h>

#define T_TOK 2048
#define HDIM 1024
#define IDIM 512
#define ISDIM 1024
#define NEXP 16
#define TOPK 4
#define NSLOT (T_TOK*TOPK)
#define SCALE_F 2.5f

typedef unsigned short u16;
typedef float f32x4 __attribute__((ext_vector_type(4)));
typedef __bf16 bf16x8 __attribute__((ext_vector_type(8)));
typedef u16 u16x8 __attribute__((ext_vector_type(8)));

__device__ __forceinline__ u16 f2bf(float f) {
  unsigned u = __builtin_bit_cast(unsigned, f);
  u += 0x7fffu + ((u >> 16) & 1u);   // round-to-nearest-even
  return (u16)(u >> 16);
}

__device__ __forceinline__ float bf2f(u16 h) {
  unsigned u = ((unsigned)h) << 16;
  return __builtin_bit_cast(float, u);
}

__device__ __forceinline__ void gload_lds16(const u16* g, u16* l) {
  // async global->LDS, 16B/lane; data lands at (wave-uniform l) + lane*16
  __builtin_amdgcn_global_load_lds(
      (const __attribute__((address_space(1))) void*)g,
      (__attribute__((address_space(3))) void*)l, 16, 0, 0);
}

__device__ __forceinline__ f32x4 mfma16(u16x8 a, u16x8 b, f32x4 c) {
  return __builtin_amdgcn_mfma_f32_16x16x32_bf16(
      __builtin_bit_cast(bf16x8, a), __builtin_bit_cast(bf16x8, b), c, 0, 0, 0);
}

// counted waits (T4): NEVER vmcnt(0) in the main loop — loads stay in
// flight across barriers. rule 18: sched_barrier(0) after lgkmcnt(0).
__device__ __forceinline__ void wait_vm6()   { asm volatile("s_waitcnt vmcnt(6)" ::: "memory"); }
__device__ __forceinline__ void wait_vm0()   { asm volatile("s_waitcnt vmcnt(0)" ::: "memory"); }
__device__ __forceinline__ void wait_lgkm0() { asm volatile("s_waitcnt lgkmcnt(0)" ::: "memory"); }

// compact tile-list sizing (worst case): sum_e ceil(cnt_e/64) <= 144
// phase0 tiles <= 144*4 + 256 = 832  -> JMAX0 = 832/8 + 32 = 136
// phase1 tiles <= 144*8 + 256 = 1408 -> JMAX1 = 1408/8 + 32 = 208
#define JMAX0 136
#define G0T (8*JMAX0)
#define JMAX1 208
#define G1T (8*JMAX1)
#define MAXG0 96
#define MAXG1 192

// weight-conversion block counts (1 float4/thread, 256 threads/block)
#define N1Q (NEXP*IDIM*HDIM/4)
#define N2Q (NEXP*HDIM*IDIM/4)
#define NSQ (ISDIM*HDIM/4)
#define CVTB ((N1Q + NSQ) / 256)        // 9216 blocks (same for phase-1 set)

__device__ __forceinline__ void cvt_f4(const float* src, u16* dst, int off) {
  float4 v = reinterpret_cast<const float4*>(src)[off];
  ushort4 o;
  o.x = f2bf(v.x); o.y = f2bf(v.y); o.z = f2bf(v.z); o.w = f2bf(v.w);
  reinterpret_cast<ushort4*>(dst)[off] = o;
}

// ---------------- router + W1/Ws1 conversion (overlapped) -----------------
// v14: v13's folded histogram REVERTED — 8192 unaggregated atomicAdds on
// one cacheline serialize at the owning L2 slice (~12ns/RMW = ~100us,
// measured 109us). Histogram back in separate wave-aggregated hist_kernel.
// Blocks >= T_TOK convert W1/Ws1 while router blocks run.
__global__ void __launch_bounds__(256) router_kernel(
    const float* __restrict__ x, const float* __restrict__ Wg,
    const float* __restrict__ bias,
    int* __restrict__ topk_idx, float* __restrict__ topk_w,
    u16* __restrict__ Xbf,
    const float* __restrict__ W1, const float* __restrict__ Ws1,
    u16* __restrict__ W1b, u16* __restrict__ Ws1b) {
  int t = blockIdx.x;
  int tid = threadIdx.x;

  if (t >= T_TOK) {            // weight-conversion blocks (block-uniform)
    int i = (t - T_TOK) * 256 + tid;
    if (i < N1Q) cvt_f4(W1, W1b, i);
    else         cvt_f4(Ws1, Ws1b, i - N1Q);
    return;
  }

  int lane = tid & 63;
  int wave = tid >> 6;

  __shared__ __align__(16) float sx[HDIM];
  __shared__ float ssc[NEXP];

  float4 xv = reinterpret_cast<const float4*>(x + (size_t)t * HDIM)[tid];
  reinterpret_cast<float4*>(sx)[tid] = xv;
  ushort4 o;
  o.x = f2bf(xv.x); o.y = f2bf(xv.y); o.z = f2bf(xv.z); o.w = f2bf(xv.w);
  reinterpret_cast<ushort4*>(Xbf + (size_t)t * HDIM)[tid] = o;
  __syncthreads();

  float acc[4] = {0.f, 0.f, 0.f, 0.f};
  const float4* sx4 = reinterpret_cast<const float4*>(sx);
#pragma unroll
  for (int c = 0; c < 4; c++) {
    float4 xq = sx4[lane + 64 * c];
#pragma unroll
    for (int e = 0; e < 4; e++) {
      float4 wq = reinterpret_cast<const float4*>(
          Wg + (size_t)(wave * 4 + e) * HDIM)[lane + 64 * c];
      acc[e] += xq.x * wq.x + xq.y * wq.y + xq.z * wq.z + xq.w * wq.w;
    }
  }
#pragma unroll
  for (int e = 0; e < 4; e++) {
    float v = acc[e];
#pragma unroll
    for (int off = 32; off > 0; off >>= 1) v += __shfl_xor(v, off);
    if (lane == 0) ssc[wave * 4 + e] = v;
  }
  __syncthreads();

  if (tid == 0) {
    float scores[NEXP], sc[NEXP];
#pragma unroll
    for (int e = 0; e < NEXP; e++) {
      float s = 1.f / (1.f + expf(-ssc[e]));
      scores[e] = s;
      sc[e] = s + bias[e];
    }
    float gsum[4];
#pragma unroll
    for (int g = 0; g < 4; g++) {
      float a = sc[4*g], b = sc[4*g+1], c = sc[4*g+2], d = sc[4*g+3];
      float hi1 = fmaxf(a, b), lo1 = fminf(a, b);
      float hi2 = fmaxf(c, d), lo2 = fminf(c, d);
      gsum[g] = fmaxf(hi1, hi2) + fmaxf(fminf(hi1, hi2), fmaxf(lo1, lo2));
    }
    int g0 = 0; float bv = gsum[0];
#pragma unroll
    for (int g = 1; g < 4; g++) if (gsum[g] > bv) { bv = gsum[g]; g0 = g; }
    int g1 = -1; float bv2 = -1e30f;
#pragma unroll
    for (int g = 0; g < 4; g++) if (g != g0 && gsum[g] > bv2) { bv2 = gsum[g]; g1 = g; }
    float m[NEXP];
#pragma unroll
    for (int e = 0; e < NEXP; e++) {
      int g = e >> 2;
      m[e] = (g == g0 || g == g1) ? sc[e] : 0.0f;
    }
    int idx[TOPK]; float w[TOPK];
#pragma unroll
    for (int k = 0; k < TOPK; k++) {
      int bj = 0; float bmv = m[0];
#pragma unroll
      for (int j = 1; j < NEXP; j++) if (m[j] > bmv) { bmv = m[j]; bj = j; }
      idx[k] = bj; w[k] = scores[bj];
#pragma unroll
      for (int j = 0; j < NEXP; j++) m[j] = (j == bj) ? -1e30f : m[j];
    }
    float s4 = w[0] + w[1] + w[2] + w[3] + 1e-20f;
    float inv = SCALE_F / s4;
#pragma unroll
    for (int k = 0; k < TOPK; k++) {
      topk_idx[t * TOPK + k] = idx[k];
      topk_w[t * TOPK + k] = w[k] * inv;
    }
  }
}

// ---------------- hist: 32 blocks, wave-aggregated global atomics ---------
// (restored from v12: <=16 leader atomics/wave, 2048 total — pipelined)
__global__ void __launch_bounds__(256) hist_kernel(
    const int* __restrict__ topk_idx, int* __restrict__ counts) {
  int j = blockIdx.x * 256 + threadIdx.x;
  int lane = threadIdx.x & 63;
  int e = topk_idx[j];
  unsigned long long m = ~0ull;
#pragma unroll
  for (int b = 0; b < 4; b++) {
    unsigned long long bb = __ballot((e >> b) & 1);
    m &= ((e >> b) & 1) ? bb : ~bb;
  }
  int leader = __ffsll(m) - 1;
  if (lane == leader) atomicAdd(&counts[e], __popcll(m));
}

// ---------------- scatter_build: 33 blocks ---------------------------------
// blocks 0-31: scatter 1 slot/thread (wave-aggregated atomics on gfill);
// block 32: greedy tile-list builders (concurrent with scatter).
// phase-1 shared expert is UNSPLIT over K (v13 keeper).
__global__ void __launch_bounds__(256) scatter_build(
    const int* __restrict__ topk_idx, const float* __restrict__ topk_w,
    const int* __restrict__ counts, int* __restrict__ offsets,
    int* __restrict__ gfill,
    int* __restrict__ perm_token, float* __restrict__ perm_w,
    int* __restrict__ slot_of,
    int* __restrict__ tiles0, int* __restrict__ tiles1) {
  int b = blockIdx.x;
  int tid = threadIdx.x;
  int lane = tid & 63;

  if (b < 32) {
    int c = (lane < NEXP) ? counts[lane] : 0;
    int incl = c;
#pragma unroll
    for (int o = 1; o < 16; o <<= 1) {
      int v = __shfl_up(incl, o);
      if (lane >= o) incl += v;
    }
    int excl = incl - c;

    int j = b * 256 + tid;
    int e = topk_idx[j];
    unsigned long long m = ~0ull;
#pragma unroll
    for (int bb = 0; bb < 4; bb++) {
      unsigned long long bl = __ballot((e >> bb) & 1);
      m &= ((e >> bb) & 1) ? bl : ~bl;
    }
    int leader = __ffsll(m) - 1;
    int rank = __popcll(m & ((1ull << lane) - 1ull));
    int base = 0;
    if (lane == leader) base = atomicAdd(&gfill[e], __popcll(m));
    base = __shfl(base, leader);
    int pos = __shfl(excl, e) + base + rank;
    perm_token[pos] = j >> 2;
    perm_w[pos] = topk_w[j];
    slot_of[j] = pos;
    if (b == 0 && tid < NEXP) offsets[tid] = excl;
    return;
  }

  __shared__ int hcnt[NEXP];
  __shared__ int g0s[MAXG0], g0c[MAXG0], g0n[MAXG0];
  __shared__ int g1s[MAXG1], g1c[MAXG1], g1n[MAXG1];
  __shared__ int sng0, sng1;
  if (tid < NEXP) hcnt[tid] = counts[tid];
  __syncthreads();

  if (tid == 0) {            // phase-0 builder (register greedy)
    int l0=0,l1=0,l2=0,l3=0,l4=0,l5=0,l6=0,l7=0;
    int ng = 0;
#define PLACE0(code0, cn)                                               \
    { int x = 0, lv = l0;                                               \
      if (l1<lv){lv=l1;x=1;} if (l2<lv){lv=l2;x=2;}                     \
      if (l3<lv){lv=l3;x=3;} if (l4<lv){lv=l4;x=4;}                     \
      if (l5<lv){lv=l5;x=5;} if (l6<lv){lv=l6;x=6;}                     \
      if (l7<lv){lv=l7;x=7;}                                            \
      g0s[ng] = x + 8*lv; g0c[ng] = (code0); g0n[ng] = (cn); ng++;      \
      if (x==0)l0+=(cn); else if (x==1)l1+=(cn); else if (x==2)l2+=(cn);\
      else if (x==3)l3+=(cn); else if (x==4)l4+=(cn);                   \
      else if (x==5)l5+=(cn); else if (x==6)l6+=(cn); else l7+=(cn); }
    for (int nb = 0; nb < 8; nb++) PLACE0((16 << 10) | nb, 32);
    for (int e = 0; e < NEXP; e++) {
      int mc = (hcnt[e] + 63) >> 6;
      for (int nb = 0; nb < 4; nb++)
        for (int base = 0; base < mc; base += 32)
          PLACE0((e << 10) | (base << 3) | nb, min(32, mc - base));
    }
    sng0 = ng;
#undef PLACE0
  }
  if (tid == 64) {           // phase-1 builder: shared UNSPLIT (8 nb-groups)
    int l0=0,l1=0,l2=0,l3=0,l4=0,l5=0,l6=0,l7=0;
    int ng = 0;
#define PLACE1(code0, cn)                                               \
    { int x = 0, lv = l0;                                               \
      if (l1<lv){lv=l1;x=1;} if (l2<lv){lv=l2;x=2;}                     \
      if (l3<lv){lv=l3;x=3;} if (l4<lv){lv=l4;x=4;}                     \
      if (l5<lv){lv=l5;x=5;} if (l6<lv){lv=l6;x=6;}                     \
      if (l7<lv){lv=l7;x=7;}                                            \
      g1s[ng] = x + 8*lv; g1c[ng] = (code0); g1n[ng] = (cn); ng++;      \
      if (x==0)l0+=(cn); else if (x==1)l1+=(cn); else if (x==2)l2+=(cn);\
      else if (x==3)l3+=(cn); else if (x==4)l4+=(cn);                   \
      else if (x==5)l5+=(cn); else if (x==6)l6+=(cn); else l7+=(cn); }
    for (int nb = 0; nb < 8; nb++) PLACE1((16 << 10) | nb, 32);
    for (int e = 0; e < NEXP; e++) {
      int mc = (hcnt[e] + 63) >> 6;
      for (int nb = 0; nb < 8; nb++)
        for (int base = 0; base < mc; base += 32)
          PLACE1((e << 10) | (base << 3) | nb, min(32, mc - base));
    }
    sng1 = ng;
#undef PLACE1
  }
  if (tid >= 128) {
    for (int i = tid - 128; i < G0T; i += 128) tiles0[i] = -1;
    for (int i = tid - 128; i < G1T; i += 128) tiles1[i] = -1;
  }
  __syncthreads();

  int ng0 = sng0, ng1 = sng1;
  for (int g = tid; g < ng0; g += 256) {
    int st = g0s[g], c0 = g0c[g], cn = g0n[g];
    for (int mm = 0; mm < cn; mm++) tiles0[st + 8 * mm] = c0 + (mm << 3);
  }
  for (int g = tid; g < ng1; g += 256) {
    int st = g1s[g], c0 = g1c[g], cn = g1n[g];
    for (int mm = 0; mm < cn; mm++) tiles1[st + 8 * mm] = c0 + (mm << 3);
  }
}

// ---------------- fused MoE GEMM: 64x128, BK=64, counted-vmcnt pipeline ----
// phase-1 shared expert UNSPLIT over K (runtime NT=16): bf16 Ysb replaces
// split-K fp32 Ys (-24MB traffic). PHASE 0 carries 9216 blocks converting
// W2/Ws2 for phase 1 (overlap).
#define BM 64
#define BN 128
#define BK 64

template<int PHASE>
__global__ void __launch_bounds__(256) moe_gemm(
    const int* __restrict__ tiles,
    const u16* __restrict__ Xbf, const u16* __restrict__ Hg,
    const u16* __restrict__ Hs,
    const u16* __restrict__ W1b, const u16* __restrict__ W2b,
    const u16* __restrict__ Ws1b, const u16* __restrict__ Ws2b,
    const float* __restrict__ W2f, const float* __restrict__ Ws2f,
    u16* __restrict__ W2bo, u16* __restrict__ Ws2bo,
    const int* __restrict__ eoffs, const int* __restrict__ ecnts,
    const int* __restrict__ rowmap, const float* __restrict__ rowscale,
    u16* __restrict__ HgOut, u16* __restrict__ HsOut,
    u16* __restrict__ Ygb, u16* __restrict__ Ysb)
{
  if (PHASE == 0 && blockIdx.x >= G0T) {   // overlapped W2/Ws2 conversion
    int i = (blockIdx.x - G0T) * 256 + threadIdx.x;
    if (i < N2Q) cvt_f4(W2f, W2bo, i);
    else         cvt_f4(Ws2f, Ws2bo, i - N2Q);
    return;
  }

  int code = tiles[blockIdx.x];
  if (code < 0) return;                            // block-uniform exit
  int e  = code >> 10;
  int mb = (code >> 3) & 127;
  int nb = code & 7;

  bool sh = (e >= NEXP);
  int N, Mloc, rowbase, Astr, Bstr;
  int NT;                                          // runtime K-tile count
  const u16* Abase;
  const u16* Bp;
  if (PHASE == 0) {
    Astr = HDIM; Bstr = HDIM; NT = HDIM / BK;
    if (sh) { N = ISDIM; Mloc = T_TOK; rowbase = 0; Abase = Xbf; Bp = Ws1b; }
    else    { N = IDIM; Mloc = ecnts[e]; rowbase = eoffs[e]; Abase = Xbf;
              Bp = W1b + (size_t)e * IDIM * HDIM; }
  } else {
    N = HDIM;
    if (sh) { Astr = ISDIM; Bstr = ISDIM; NT = ISDIM / BK;   // unsplit K
              Mloc = T_TOK; rowbase = 0; Abase = Hs; Bp = Ws2b; }
    else    { Astr = IDIM; Bstr = IDIM; NT = IDIM / BK;
              Mloc = ecnts[e]; rowbase = eoffs[e]; Abase = Hg;
              Bp = W2b + (size_t)e * HDIM * IDIM; }
  }
  int m0 = mb * BM;
  if (m0 >= Mloc) return;
  int n0 = nb * BN;
  if (n0 >= N) return;

  // unpadded: required by global_load_lds lane->base+lane*16 placement
  __shared__ __align__(16) u16 sA[2][BM * BK];   // 2 x 8 KB
  __shared__ __align__(16) u16 sB[2][BN * BK];   // 2 x 16 KB

  int tid = threadIdx.x;
  int lane = tid & 63;
  int wave = tid >> 6;
  int wm = (wave >> 1) * 32;   // wave computes 32x64 of the 64x128 tile
  int wn = (wave & 1) * 64;
  int fm = lane & 15;
  int kq = lane >> 4;          // 0..3
  int fsw = fm & 7;            // row&7 for fragment-row fm

  // staging: lane -> row (lane>>3), LDS chunk (lane&7); source chunk is
  // XOR-swizzled so LDS chunk l of row r holds global chunk l ^ (r&7)
  int lrow8 = lane >> 3;       // 0..7
  int sch = ((lane & 7) ^ lrow8) * 8;   // swizzled source k-offset (elems)

  // A: wave stages tile rows [16w,16w+16) via 2 gloads of 8 rows
  const u16* AgP[2];
  int aoff[2];
#pragma unroll
  for (int g = 0; g < 2; g++) {
    int rt = 16 * wave + 8 * g + lrow8;
    int ar = m0 + rt;
    int arc = (ar < Mloc) ? ar : (Mloc - 1);        // clamp; stores masked
    size_t asrc;
    if (PHASE == 0 && !sh) asrc = (size_t)rowmap[rowbase + arc] * Astr;
    else                   asrc = (size_t)((sh ? 0 : rowbase) + arc) * Astr;
    AgP[g] = Abase + asrc + sch;
    aoff[g] = (16 * wave + 8 * g) * BK;
  }
  // B: wave stages tile rows [32w,32w+32) via 4 gloads of 8 rows
  const u16* BgP[4];
  int boff[4];
#pragma unroll
  for (int g = 0; g < 4; g++) {
    int rt = 32 * wave + 8 * g + lrow8;
    BgP[g] = Bp + (size_t)(n0 + rt) * Bstr + sch;
    boff[g] = (32 * wave + 8 * g) * BK;
  }

  f32x4 acc[2][4] = {};

  // prologue: stage tiles 0 and 1 (6 gloads each, per wave)
#pragma unroll
  for (int g = 0; g < 2; g++) gload_lds16(AgP[g], &sA[0][aoff[g]]);
#pragma unroll
  for (int g = 0; g < 4; g++) gload_lds16(BgP[g], &sB[0][boff[g]]);
#pragma unroll
  for (int g = 0; g < 2; g++) gload_lds16(AgP[g] + BK, &sA[1][aoff[g]]);
#pragma unroll
  for (int g = 0; g < 4; g++) gload_lds16(BgP[g] + BK, &sB[1][boff[g]]);

  // main loop: tiles 0..NT-2 with counted vmcnt(6); tail tile drains
  for (int t = 0; t < NT - 1; ++t) {
    int cur = t & 1;
    wait_vm6();                        // tile t's 6 done; t+1's 6 in flight
    __builtin_amdgcn_s_barrier();      // all waves: buf[cur] fully staged
    u16x8 af[2][2], bf[2][4];
#pragma unroll
    for (int ks = 0; ks < 2; ks++) {
      int ch = ((ks * 4 + kq) ^ fsw) * 8;   // un-swizzle at read
#pragma unroll
      for (int i = 0; i < 2; i++)
        af[ks][i] = *reinterpret_cast<const u16x8*>(&sA[cur][(wm + 16 * i + fm) * BK + ch]);
#pragma unroll
      for (int j = 0; j < 4; j++)
        bf[ks][j] = *reinterpret_cast<const u16x8*>(&sB[cur][(wn + 16 * j + fm) * BK + ch]);
    }
    wait_lgkm0();
    __builtin_amdgcn_sched_barrier(0);  // rule 18: pin MFMA below the wait
    __builtin_amdgcn_s_barrier();       // all waves done reading buf[cur]
    if (t + 2 < NT) {                   // overwrite buf[cur] with tile t+2
#pragma unroll
      for (int g = 0; g < 2; g++) gload_lds16(AgP[g] + (t + 2) * BK, &sA[cur][aoff[g]]);
#pragma unroll
      for (int g = 0; g < 4; g++) gload_lds16(BgP[g] + (t + 2) * BK, &sB[cur][boff[g]]);
    }
#pragma unroll
    for (int ks = 0; ks < 2; ks++)
#pragma unroll
      for (int i = 0; i < 2; i++)
#pragma unroll
        for (int j = 0; j < 4; j++)
          acc[i][j] = mfma16(af[ks][i], bf[ks][j], acc[i][j]);
  }
  {  // tail: tile NT-1 (only its 6 loads remain in flight)
    int cur = (NT - 1) & 1;
    wait_vm0();
    __builtin_amdgcn_s_barrier();
    u16x8 af[2][2], bf[2][4];
#pragma unroll
    for (int ks = 0; ks < 2; ks++) {
      int ch = ((ks * 4 + kq) ^ fsw) * 8;
#pragma unroll
      for (int i = 0; i < 2; i++)
        af[ks][i] = *reinterpret_cast<const u16x8*>(&sA[cur][(wm + 16 * i + fm) * BK + ch]);
#pragma unroll
      for (int j = 0; j < 4; j++)
        bf[ks][j] = *reinterpret_cast<const u16x8*>(&sB[cur][(wn + 16 * j + fm) * BK + ch]);
    }
    wait_lgkm0();
    __builtin_amdgcn_sched_barrier(0);
#pragma unroll
    for (int ks = 0; ks < 2; ks++)
#pragma unroll
      for (int i = 0; i < 2; i++)
#pragma unroll
        for (int j = 0; j < 4; j++)
          acc[i][j] = mfma16(af[ks][i], bf[ks][j], acc[i][j]);
  }

  // epilogue: C/D mapping col = lane&15, row = (lane>>4)*4 + reg (m89/m91)
#pragma unroll
  for (int i = 0; i < 2; i++) {
#pragma unroll
    for (int r = 0; r < 4; r++) {
      int gm = m0 + wm + 16 * i + kq * 4 + r;
      if (gm < Mloc) {
        float rs = 0.f;
        if (PHASE == 0 && !sh) rs = rowscale[rowbase + gm];
#pragma unroll
        for (int j = 0; j < 4; j++) {
          int gn = n0 + wn + 16 * j + fm;
          float v = acc[i][j][r];
          if (PHASE == 0) {
            float tq = fmaxf(v, 0.f);
            if (!sh) {
              tq = tq * tq * rs;
              HgOut[(size_t)(rowbase + gm) * IDIM + gn] = f2bf(tq);
            } else {
              HsOut[(size_t)gm * ISDIM + gn] = f2bf(tq * tq);
            }
          } else {
            if (!sh) Ygb[(size_t)(rowbase + gm) * HDIM + gn] = f2bf(v);
            else     Ysb[(size_t)gm * HDIM + gn] = f2bf(v);   // unsplit
          }
        }
      }
    }
  }
}

// ---- combine: out[t] = Ysb[t] + sum_k Ygb[slot_of[t,k]] (all bf16) -------
__global__ void __launch_bounds__(256) combine_kernel(
    const u16* __restrict__ Ygb, const u16* __restrict__ Ysb,
    const int* __restrict__ slot_of, float* __restrict__ out) {
  int t = blockIdx.x;
  int i = threadIdx.x;                       // 256 x 4 elems = 1024
  int4 s = *reinterpret_cast<const int4*>(&slot_of[t * 4]);
  const ushort4* Y4 = reinterpret_cast<const ushort4*>(Ygb);
  const ushort4* S4 = reinterpret_cast<const ushort4*>(Ysb);
  float4* O4 = reinterpret_cast<float4*>(out);
  ushort4 sv = S4[(size_t)t * 256 + i];
  ushort4 a = Y4[(size_t)s.x * 256 + i];
  ushort4 b = Y4[(size_t)s.y * 256 + i];
  ushort4 c = Y4[(size_t)s.z * 256 + i];
  ushort4 d = Y4[(size_t)s.w * 256 + i];
  float4 v;
  v.x = bf2f(sv.x) + bf2f(a.x) + bf2f(b.x) + bf2f(c.x) + bf2f(d.x);
  v.y = bf2f(sv.y) + bf2f(a.y) + bf2f(b.y) + bf2f(c.y) + bf2f(d.y);
  v.z = bf2f(sv.z) + bf2f(a.z) + bf2f(b.z) + bf2f(c.z) + bf2f(d.z);
  v.w = bf2f(sv.w) + bf2f(a.w) + bf2f(b.w) + bf2f(c.w) + bf2f(d.w);
  O4[(size_t)t * 256 + i] = v;
}

// ---------------- launcher ----------------
extern "C" void kernel_launch(void* const* d_in, const int* in_sizes, int n_in,
                              void* d_out, int out_size, void* d_ws, size_t ws_size,
                              hipStream_t stream) {
  const float* x    = (const float*)d_in[0];
  const float* Wg   = (const float*)d_in[1];
  const float* bias = (const float*)d_in[2];
  const float* W1   = (const float*)d_in[3];
  const float* W2   = (const float*)d_in[4];
  const float* Ws1  = (const float*)d_in[5];
  const float* Ws2  = (const float*)d_in[6];
  float* out = (float*)d_out;

  char* p = (char*)d_ws;
  auto alloc = [&](size_t bytes) -> void* {
    void* r = (void*)p;
    p += (bytes + 255) & ~(size_t)255;
    return r;
  };
  int*   topk_idx   = (int*)  alloc((size_t)NSLOT * 4);
  float* topk_w     = (float*)alloc((size_t)NSLOT * 4);
  int*   counts     = (int*)  alloc(64);     // ┐ contiguous 256B-aligned
  int*   offsets    = (int*)  alloc(64);     // │ trio zeroed by one memset
  int*   gfill      = (int*)  alloc(64);     // ┘ (offsets rewritten later)
  int*   perm_token = (int*)  alloc((size_t)NSLOT * 4);
  float* perm_w     = (float*)alloc((size_t)NSLOT * 4);
  int*   slot_of    = (int*)  alloc((size_t)NSLOT * 4);
  int*   tiles0     = (int*)  alloc((size_t)G0T * 4);
  int*   tiles1     = (int*)  alloc((size_t)G1T * 4);
  u16*   Xbf        = (u16*)  alloc((size_t)T_TOK * HDIM * 2);
  u16*   W1b        = (u16*)  alloc((size_t)NEXP * IDIM * HDIM * 2);
  u16*   W2b        = (u16*)  alloc((size_t)NEXP * HDIM * IDIM * 2);
  u16*   Ws1b      = (u16*)  alloc((size_t)ISDIM * HDIM * 2);
  u16*   Ws2b      = (u16*)  alloc((size_t)HDIM * ISDIM * 2);
  u16*   Hg         = (u16*)  alloc((size_t)NSLOT * IDIM * 2);
  u16*   Hs         = (u16*)  alloc((size_t)T_TOK * ISDIM * 2);
  u16*   Ygb        = (u16*)  alloc((size_t)NSLOT * HDIM * 2);
  u16*   Ysb        = (u16*)  alloc((size_t)T_TOK * HDIM * 2);

  // zero counts/offsets/gfill (contiguous 3x256B region from counts)
  hipMemsetAsync(counts, 0, 768, stream);

  // router + overlapped W1/Ws1 conversion (no atomics in router)
  router_kernel<<<T_TOK + CVTB, 256, 0, stream>>>(
      x, Wg, bias, topk_idx, topk_w, Xbf, W1, Ws1, W1b, Ws1b);
  hist_kernel<<<32, 256, 0, stream>>>(topk_idx, counts);
  scatter_build<<<33, 256, 0, stream>>>(topk_idx, topk_w, counts, offsets,
                                        gfill, perm_token, perm_w, slot_of,
                                        tiles0, tiles1);

  // phase A: routed up + shared up, plus overlapped W2/Ws2 conversion
  moe_gemm<0><<<G0T + CVTB, 256, 0, stream>>>(
      tiles0, Xbf, Hg, Hs, W1b, W2b, Ws1b, Ws2b, W2, Ws2, W2b, Ws2b,
      offsets, counts, perm_token, perm_w, Hg, Hs, nullptr, nullptr);

  // phase B: routed down (K=512) + shared down UNSPLIT (K=1024)
  moe_gemm<1><<<G1T, 256, 0, stream>>>(
      tiles1, Xbf, Hg, Hs, W1b, W2b, Ws1b, Ws2b, W2, Ws2, W2b, Ws2b,
      offsets, counts, perm_token, perm_w, Hg, Hs, Ygb, Ysb);

  // combine: out[t] = Ysb + sum_k Ygb[slot_of[t,k]]
  combine_kernel<<<T_TOK, 256, 0, stream>>>(Ygb, Ysb, slot_of, out);
}